// Round 15
// baseline (181.612 us; speedup 1.0000x reference)
//
#include <hip/hip_runtime.h>
#include <hip/hip_bf16.h>

#define GN 4096
#define GF 512
#define GH 8
#define GC 128
#define CAP 256          // max stored neighbors/row; deg ~ Bin(4096,0.01) = 41±6.4
#define XS 72            // padded LDS row stride (u16): 144 B, 16B-aligned

typedef __hip_bfloat16 bf16;
typedef unsigned short u16;
typedef unsigned int u32;
typedef __attribute__((ext_vector_type(8))) short bf16x8;   // 8 bf16 = 4 VGPRs
typedef __attribute__((ext_vector_type(4))) float f32x4;

static __device__ inline u16 f2u16(float x) {
    union { bf16 b; u16 u; } cv;
    cv.b = __float2bfloat16(x);
    return cv.u;
}

// ---------------------------------------------------------------------------
// Kernel 1 (fused prep + csr — r10-verified): heterogeneous block ranges
// with COMPATIBLE resource footprints. Blocks [0,1024): X fp32->bf16.
// [1024,1088): W transpose to WT[h][n][k]. [1088,5184): csr — A row ->
// compact u16 neighbor list via wave-ballot compaction (MASK_VAL=-1e10
// makes non-neighbor exp() underflow to exactly 0 in fp32, so
// neighbor-only softmax is exact).
// ---------------------------------------------------------------------------
__global__ __launch_bounds__(256) void prep_csr_kernel(
    const float* __restrict__ A, const float* __restrict__ X,
    const float* __restrict__ W, int* __restrict__ deg,
    u16* __restrict__ lists, u16* __restrict__ Xb, u16* __restrict__ WT)
{
    __shared__ u16 sT[16][520];            // 16.6 KB; csr aliases sT[0..1] as cnt
    int tid = threadIdx.x;
    int b   = blockIdx.x;

    if (b < 1024) {
        size_t idx = ((size_t)b * 256 + tid) * 8;
        float4 v0 = *(const float4*)(X + idx);
        float4 v1 = *(const float4*)(X + idx + 4);
        u16 o[8] = {f2u16(v0.x), f2u16(v0.y), f2u16(v0.z), f2u16(v0.w),
                    f2u16(v1.x), f2u16(v1.y), f2u16(v1.z), f2u16(v1.w)};
        *(bf16x8*)(Xb + idx) = *(bf16x8*)o;
        return;
    }
    if (b < 1088) {
        int wb = b - 1024;                 // 0..63
        int h  = wb >> 3;
        int s16 = (wb & 7) * 16;
        const float* Wh = W + (size_t)h * GF * GC;
        for (int pass = 0; pass < 8; ++pass) {
            int k  = pass * 64 + (tid >> 2);
            int n4 = tid & 3;
            float4 v = *(const float4*)&Wh[(size_t)k * GC + s16 + n4 * 4];
            sT[n4 * 4 + 0][k] = f2u16(v.x);
            sT[n4 * 4 + 1][k] = f2u16(v.y);
            sT[n4 * 4 + 2][k] = f2u16(v.z);
            sT[n4 * 4 + 3][k] = f2u16(v.w);
        }
        __syncthreads();
        int n = tid >> 4, seg = tid & 15;
        u16* dst = WT + ((size_t)h * GC + s16 + n) * GF + seg * 32;
#pragma unroll
        for (int s = 0; s < 4; ++s)
            *(bf16x8*)(dst + s * 8) = *(const bf16x8*)&sT[n][seg * 32 + s * 8];
        return;
    }

    // ---- csr: row i ----
    int i    = b - 1088;
    int lane = tid & 63;
    int* cnt = (int*)&sT[0][0];
    if (tid == 0) *cnt = 0;
    __syncthreads();

    u16* row = lists + (size_t)i * CAP;
    const float4* Arow = (const float4*)(A + (size_t)i * GN);
    unsigned long long ltmask = (lane == 63) ? ~0ull >> 1
                                             : (1ull << lane) - 1;
#pragma unroll
    for (int it = 0; it < 4; ++it) {
        int qd = it * 256 + tid;
        float4 a = Arow[qd];
        int j = qd * 4;
#pragma unroll
        for (int comp = 0; comp < 4; ++comp) {
            float av = comp == 0 ? a.x : comp == 1 ? a.y : comp == 2 ? a.z : a.w;
            bool flag = av > 0.5f;
            unsigned long long m = __ballot(flag);
            if (m) {
                int base = 0;
                if (lane == 0) base = atomicAdd(cnt, __popcll(m));
                base = __shfl(base, 0);
                if (flag) {
                    int s = base + __popcll(m & ltmask);
                    if (s < CAP) row[s] = (u16)(j + comp);
                }
            }
        }
    }
    __syncthreads();
    if (tid == 0) deg[i] = *cnt < CAP ? *cnt : CAP;
}

// ---------------------------------------------------------------------------
// Kernel 2 (MFMA feats, LDS-tiled x col-split): the r9 low-traffic LDS
// tiling (≈130 MB) COMBINED with r8's high occupancy. BM=64, BN=64, BK=64
// -> 1024 blocks (h x col-half x 64 n-tiles), LDS 18.4 KB -> ~6-8 blocks/CU
// (20-24 waves/CU vs r9's 8): feats was latency-bound at 2 blocks/CU
// (throughput floor ~5 us vs ~35 us measured), so occupancy is the lever.
// Score vectors are per-col-half partials (r8-proven); attn sums them.
// ---------------------------------------------------------------------------
__global__ __launch_bounds__(256) void feats_kernel(
    const u16* __restrict__ Xb, const u16* __restrict__ WT,
    const float* __restrict__ a_self, const float* __restrict__ a_neigh,
    bf16* __restrict__ featsb, float* __restrict__ s_selfP,
    float* __restrict__ s_neighP)
{
    __shared__ u16 sX[64 * XS];    // 9.2 KB
    __shared__ u16 sW[64 * XS];    // 9.2 KB

    int h   = blockIdx.x >> 7;
    int ch  = (blockIdx.x >> 6) & 1;
    int n0  = (blockIdx.x & 63) << 6;
    int tid = threadIdx.x;
    int lane = tid & 63, wv = tid >> 6;
    int lm = lane & 15, q = lane >> 4;

    const u16* Xp = Xb + (size_t)n0 * GF;
    const u16* Wp = WT + ((size_t)h * GC + ch * 64) * GF;

    uint4 xr[2], wr[2];

#define ISSUE_TILE(K0)                                                        \
    {                                                                         \
        _Pragma("unroll")                                                     \
        for (int it = 0; it < 2; ++it) {                                      \
            int idx = it * 256 + tid, row = idx >> 3, c = idx & 7;            \
            xr[it] = *(const uint4*)&Xp[(size_t)row * GF + (K0) + c * 8];     \
            wr[it] = *(const uint4*)&Wp[(size_t)row * GF + (K0) + c * 8];     \
        }                                                                     \
    }

#define STORE_TILE()                                                          \
    {                                                                         \
        _Pragma("unroll")                                                     \
        for (int it = 0; it < 2; ++it) {                                      \
            int idx = it * 256 + tid, row = idx >> 3, c = idx & 7;            \
            *(uint4*)&sX[row * XS + c * 8] = xr[it];                          \
            *(uint4*)&sW[row * XS + c * 8] = wr[it];                          \
        }                                                                     \
    }

    f32x4 acc[4];
#pragma unroll
    for (int nt = 0; nt < 4; ++nt) acc[nt] = (f32x4){0.f, 0.f, 0.f, 0.f};

    ISSUE_TILE(0)
    STORE_TILE()

    for (int k0 = 0; k0 < GF; k0 += 64) {
        __syncthreads();                       // tile k0 visible
        if (k0 + 64 < GF) ISSUE_TILE(k0 + 64)  // next tile in flight

#pragma unroll
        for (int ks = 0; ks < 64; ks += 32) {
            bf16x8 af = *(const bf16x8*)&sX[(wv * 16 + lm) * XS + ks + q * 8];
            bf16x8 bfr[4];
#pragma unroll
            for (int nt = 0; nt < 4; ++nt)
                bfr[nt] = *(const bf16x8*)&sW[(nt * 16 + lm) * XS + ks + q * 8];
#pragma unroll
            for (int nt = 0; nt < 4; ++nt)
                acc[nt] = __builtin_amdgcn_mfma_f32_16x16x32_bf16(
                    af, bfr[nt], acc[nt], 0, 0, 0);
        }
        __syncthreads();                       // readers done
        if (k0 + 64 < GF) STORE_TILE()
    }
#undef ISSUE_TILE
#undef STORE_TILE

    // epilogue: bf16 feats store + per-half partial score vectors
    float aS[4], aN[4];
#pragma unroll
    for (int nt = 0; nt < 4; ++nt) {
        aS[nt] = a_self[h * GC + ch * 64 + nt * 16 + lm];
        aN[nt] = a_neigh[h * GC + ch * 64 + nt * 16 + lm];
    }
    float vs[4] = {0.f, 0.f, 0.f, 0.f};
    float vn[4] = {0.f, 0.f, 0.f, 0.f};
    int rbase = n0 + wv * 16 + q * 4;          // D row = quad*4+reg (m89)
#pragma unroll
    for (int nt = 0; nt < 4; ++nt) {
        f32x4 v = acc[nt];
        int col = ch * 64 + nt * 16 + lm;      // D col = lane&15
#pragma unroll
        for (int r = 0; r < 4; ++r) {
            featsb[((size_t)h * GN + rbase + r) * GC + col] = __float2bfloat16(v[r]);
            vs[r] += v[r] * aS[nt];
            vn[r] += v[r] * aN[nt];
        }
    }
#pragma unroll
    for (int r = 0; r < 4; ++r) {
        for (int off = 1; off < 16; off <<= 1) {
            vs[r] += __shfl_xor(vs[r], off);
            vn[r] += __shfl_xor(vn[r], off);
        }
        if (lm == 0) {
            s_selfP[(ch * GH + h) * GN + rbase + r]  = vs[r];
            s_neighP[(ch * GH + h) * GN + rbase + r] = vn[r];
        }
    }
}

// ---------------------------------------------------------------------------
// Kernel 3 (attn — r13-measured-best 2-head version, adapted to partial
// score vectors): ONE WAVE per (2 heads, i), 16384 waves -> 4096 blocks.
// List loaded once per wave; gather from two head-slabs per neighbor
// (2 independent loads in flight); even/odd-k split accumulators. Zero
// barriers; wave-shuffle softmax.
// ---------------------------------------------------------------------------
__global__ __launch_bounds__(256) void attn_kernel(
    const int* __restrict__ deg, const u16* __restrict__ lists,
    const float* __restrict__ bias, const bf16* __restrict__ featsb,
    const float* __restrict__ s_selfP, const float* __restrict__ s_neighP,
    float* __restrict__ out)
{
    int tid  = threadIdx.x;
    int wv   = tid >> 6, lane = tid & 63;
    int g    = blockIdx.x * 4 + wv;        // 0..16383, head-pair-major
    int hp   = g >> 12;                    // 0..3
    int i    = g & (GN - 1);
    int h0   = hp * 2, h1 = h0 + 1;

    __shared__ float4 pjbuf[4][CAP];       // 16 KB
    float4* pj = pjbuf[wv];

    int M = deg[i];
    const u16* row = lists + (size_t)i * CAP;
    float ssi0 = s_selfP[h0 * GN + i] + s_selfP[(GH + h0) * GN + i];
    float ssi1 = s_selfP[h1 * GN + i] + s_selfP[(GH + h1) * GN + i];
    const float* sn0A = s_neighP + (size_t)h0 * GN;
    const float* sn0B = s_neighP + (size_t)(GH + h0) * GN;
    const float* sn1A = s_neighP + (size_t)h1 * GN;
    const float* sn1B = s_neighP + (size_t)(GH + h1) * GN;

    // pass 1: leaky scores for both heads -> LDS, lane-local max
    float m0 = -1e30f, m1 = -1e30f;
    for (int k = lane; k < M; k += 64) {
        int j = row[k];
        float e0 = ssi0 + sn0A[j] + sn0B[j]; e0 = e0 > 0.f ? e0 : 0.2f * e0;
        float e1 = ssi1 + sn1A[j] + sn1B[j]; e1 = e1 > 0.f ? e1 : 0.2f * e1;
        pj[k] = make_float4(e0, e1, __int_as_float(j), 0.f);
        m0 = fmaxf(m0, e0);
        m1 = fmaxf(m1, e1);
    }
#pragma unroll
    for (int off = 32; off > 0; off >>= 1) {
        m0 = fmaxf(m0, __shfl_xor(m0, off));
        m1 = fmaxf(m1, __shfl_xor(m1, off));
    }

    // pass 2: exp in place + sums
    float s0 = 0.f, s1 = 0.f;
    for (int k = lane; k < M; k += 64) {
        float4 v = pj[k];
        float e0 = __expf(v.x - m0);
        float e1 = __expf(v.y - m1);
        pj[k].x = e0;
        pj[k].y = e1;
        s0 += e0;
        s1 += e1;
    }
#pragma unroll
    for (int off = 32; off > 0; off >>= 1) {
        s0 += __shfl_xor(s0, off);
        s1 += __shfl_xor(s1, off);
    }
    float inv0 = 1.f / s0, inv1 = 1.f / s1;

    // gather: lane owns dword (channels 2*lane, 2*lane+1) in both head slabs
    const u32* f0 = (const u32*)(featsb + (size_t)h0 * GN * GC) + lane;
    const u32* f1 = (const u32*)(featsb + (size_t)h1 * GN * GC) + lane;
    float aE0 = 0.f, aE1 = 0.f, bE0 = 0.f, bE1 = 0.f;   // even k
    float aO0 = 0.f, aO1 = 0.f, bO0 = 0.f, bO1 = 0.f;   // odd k
    int k = 0;
    for (; k + 2 <= M; k += 2) {
        float4 v0 = pj[k], v1 = pj[k + 1];
        int j0 = __float_as_int(v0.z), j1 = __float_as_int(v1.z);
        u32 u00 = f0[(size_t)j0 << 6];
        u32 u10 = f1[(size_t)j0 << 6];
        u32 u01 = f0[(size_t)j1 << 6];
        u32 u11 = f1[(size_t)j1 << 6];
        aE0 += v0.x * __uint_as_float(u00 << 16);
        aE1 += v0.x * __uint_as_float(u00 & 0xffff0000u);
        bE0 += v0.y * __uint_as_float(u10 << 16);
        bE1 += v0.y * __uint_as_float(u10 & 0xffff0000u);
        aO0 += v1.x * __uint_as_float(u01 << 16);
        aO1 += v1.x * __uint_as_float(u01 & 0xffff0000u);
        bO0 += v1.y * __uint_as_float(u11 << 16);
        bO1 += v1.y * __uint_as_float(u11 & 0xffff0000u);
    }
    if (k < M) {
        float4 v0 = pj[k];
        int j0 = __float_as_int(v0.z);
        u32 u00 = f0[(size_t)j0 << 6];
        u32 u10 = f1[(size_t)j0 << 6];
        aE0 += v0.x * __uint_as_float(u00 << 16);
        aE1 += v0.x * __uint_as_float(u00 & 0xffff0000u);
        bE0 += v0.y * __uint_as_float(u10 << 16);
        bE1 += v0.y * __uint_as_float(u10 & 0xffff0000u);
    }

    const float2 bv0 = *(const float2*)&bias[h0 * GC + 2 * lane];
    const float2 bv1 = *(const float2*)&bias[h1 * GC + 2 * lane];
    size_t ob = (size_t)i * (GH * GC);
    float2* op0 = (float2*)&out[ob + h0 * GC + 2 * lane];
    float2* op1 = (float2*)&out[ob + h1 * GC + 2 * lane];
    *op0 = make_float2(fmaxf((aE0 + aO0) * inv0 + bv0.x, 0.f),
                       fmaxf((aE1 + aO1) * inv0 + bv0.y, 0.f));
    *op1 = make_float2(fmaxf((bE0 + bO0) * inv1 + bv1.x, 0.f),
                       fmaxf((bE1 + bO1) * inv1 + bv1.y, 0.f));
}

// ---------------------------------------------------------------------------
extern "C" void kernel_launch(void* const* d_in, const int* in_sizes, int n_in,
                              void* d_out, int out_size, void* d_ws, size_t ws_size,
                              hipStream_t stream)
{
    const float* X       = (const float*)d_in[0];
    const float* A       = (const float*)d_in[1];
    const float* W       = (const float*)d_in[2];
    const float* a_self  = (const float*)d_in[3];
    const float* a_neigh = (const float*)d_in[4];
    const float* bias    = (const float*)d_in[5];
    float* out = (float*)d_out;

    // ws layout: featsb bf16 [H*N*C] | s_selfP f32 [2*H*N] | s_neighP f32
    //            [2*H*N] | deg i32 [N] | lists u16 [N*CAP] | Xb u16 [N*F]
    //            | WT u16 [H*C*F]
    bf16*  featsb   = (bf16*)d_ws;
    float* s_selfP  = (float*)(featsb + (size_t)GH * GN * GC);
    float* s_neighP = s_selfP + (size_t)2 * GH * GN;
    int*   deg      = (int*)(s_neighP + (size_t)2 * GH * GN);
    u16*   lists    = (u16*)(deg + GN);
    u16*   Xb       = lists + (size_t)GN * CAP;
    u16*   WT       = Xb + (size_t)GN * GF;

    prep_csr_kernel<<<1088 + GN, 256, 0, stream>>>(A, X, W, deg, lists, Xb, WT);
    feats_kernel<<<GH * 2 * 64, 256, 0, stream>>>(Xb, WT, a_self, a_neigh,
                                                  featsb, s_selfP, s_neighP);
    attn_kernel<<<GH * GN / 8, 256, 0, stream>>>(deg, lists, bias, featsb,
                                                 s_selfP, s_neighP, out);
}

// Round 16
// 170.832 us; speedup vs baseline: 1.0631x; 1.0631x over previous
//
#include <hip/hip_runtime.h>
#include <hip/hip_bf16.h>

#define GN 4096
#define GF 512
#define GH 8
#define GC 128
#define CAP 256          // max stored neighbors/row; deg ~ Bin(4096,0.01) = 41±6.4
#define XS 72            // padded LDS row stride (u16): 144 B, 16B-aligned

typedef __hip_bfloat16 bf16;
typedef unsigned short u16;
typedef unsigned int u32;
typedef __attribute__((ext_vector_type(8))) short bf16x8;   // 8 bf16 = 4 VGPRs
typedef __attribute__((ext_vector_type(4))) float f32x4;

static __device__ inline u16 f2u16(float x) {
    union { bf16 b; u16 u; } cv;
    cv.b = __float2bfloat16(x);
    return cv.u;
}

// ---------------------------------------------------------------------------
// Kernel 1 (fused prep + csr — r10-verified): heterogeneous block ranges
// with COMPATIBLE resource footprints. Blocks [0,1024): X fp32->bf16.
// [1024,1088): W transpose to WT[h][n][k]. [1088,5184): csr — A row ->
// compact u16 neighbor list via wave-ballot compaction (MASK_VAL=-1e10
// makes non-neighbor exp() underflow to exactly 0 in fp32, so
// neighbor-only softmax is exact).
// ---------------------------------------------------------------------------
__global__ __launch_bounds__(256) void prep_csr_kernel(
    const float* __restrict__ A, const float* __restrict__ X,
    const float* __restrict__ W, int* __restrict__ deg,
    u16* __restrict__ lists, u16* __restrict__ Xb, u16* __restrict__ WT)
{
    __shared__ u16 sT[16][520];            // 16.6 KB; csr aliases sT[0..1] as cnt
    int tid = threadIdx.x;
    int b   = blockIdx.x;

    if (b < 1024) {
        size_t idx = ((size_t)b * 256 + tid) * 8;
        float4 v0 = *(const float4*)(X + idx);
        float4 v1 = *(const float4*)(X + idx + 4);
        u16 o[8] = {f2u16(v0.x), f2u16(v0.y), f2u16(v0.z), f2u16(v0.w),
                    f2u16(v1.x), f2u16(v1.y), f2u16(v1.z), f2u16(v1.w)};
        *(bf16x8*)(Xb + idx) = *(bf16x8*)o;
        return;
    }
    if (b < 1088) {
        int wb = b - 1024;                 // 0..63
        int h  = wb >> 3;
        int s16 = (wb & 7) * 16;
        const float* Wh = W + (size_t)h * GF * GC;
        for (int pass = 0; pass < 8; ++pass) {
            int k  = pass * 64 + (tid >> 2);
            int n4 = tid & 3;
            float4 v = *(const float4*)&Wh[(size_t)k * GC + s16 + n4 * 4];
            sT[n4 * 4 + 0][k] = f2u16(v.x);
            sT[n4 * 4 + 1][k] = f2u16(v.y);
            sT[n4 * 4 + 2][k] = f2u16(v.z);
            sT[n4 * 4 + 3][k] = f2u16(v.w);
        }
        __syncthreads();
        int n = tid >> 4, seg = tid & 15;
        u16* dst = WT + ((size_t)h * GC + s16 + n) * GF + seg * 32;
#pragma unroll
        for (int s = 0; s < 4; ++s)
            *(bf16x8*)(dst + s * 8) = *(const bf16x8*)&sT[n][seg * 32 + s * 8];
        return;
    }

    // ---- csr: row i ----
    int i    = b - 1088;
    int lane = tid & 63;
    int* cnt = (int*)&sT[0][0];
    if (tid == 0) *cnt = 0;
    __syncthreads();

    u16* row = lists + (size_t)i * CAP;
    const float4* Arow = (const float4*)(A + (size_t)i * GN);
    unsigned long long ltmask = (lane == 63) ? ~0ull >> 1
                                             : (1ull << lane) - 1;
#pragma unroll
    for (int it = 0; it < 4; ++it) {
        int qd = it * 256 + tid;
        float4 a = Arow[qd];
        int j = qd * 4;
#pragma unroll
        for (int comp = 0; comp < 4; ++comp) {
            float av = comp == 0 ? a.x : comp == 1 ? a.y : comp == 2 ? a.z : a.w;
            bool flag = av > 0.5f;
            unsigned long long m = __ballot(flag);
            if (m) {
                int base = 0;
                if (lane == 0) base = atomicAdd(cnt, __popcll(m));
                base = __shfl(base, 0);
                if (flag) {
                    int s = base + __popcll(m & ltmask);
                    if (s < CAP) row[s] = (u16)(j + comp);
                }
            }
        }
    }
    __syncthreads();
    if (tid == 0) deg[i] = *cnt < CAP ? *cnt : CAP;
}

// ---------------------------------------------------------------------------
// Kernel 2 (MFMA feats — r9/r13-verified best): feats = Xb @ WT^T.
// BM=64 BN=128 BK=64 -> 512 blocks. BN=128 is REQUIRED: each block must
// write full 256 B feats lines — the r15 BN=64 col-split let two blocks
// (often on different XCDs, non-coherent L2s) each write half a line,
// causing 11x HBM write amplification (WRITE_SIZE 8.4 -> 95.9 MB).
// Staging = pure uint4 copies, software-pipelined; frag reads use the
// m92-verified stride-72 pattern.
// ---------------------------------------------------------------------------
__global__ __launch_bounds__(256) void feats_kernel(
    const u16* __restrict__ Xb, const u16* __restrict__ WT,
    const float* __restrict__ a_self, const float* __restrict__ a_neigh,
    bf16* __restrict__ featsb, float* __restrict__ s_self,
    float* __restrict__ s_neigh)
{
    __shared__ u16 sX[64 * XS];    //  9.2 KB
    __shared__ u16 sW[128 * XS];   // 18.4 KB

    int h   = blockIdx.x >> 6;
    int n0  = (blockIdx.x & 63) << 6;
    int tid = threadIdx.x;
    int lane = tid & 63, wv = tid >> 6;
    int lm = lane & 15, q = lane >> 4;

    const u16* Xp = Xb + (size_t)n0 * GF;
    const u16* Wp = WT + (size_t)h * GC * GF;

    uint4 xr[2], wr[4];

#define ISSUE_TILE(K0)                                                        \
    {                                                                         \
        _Pragma("unroll")                                                     \
        for (int it = 0; it < 2; ++it) {                                      \
            int idx = it * 256 + tid, row = idx >> 3, c = idx & 7;            \
            xr[it] = *(const uint4*)&Xp[(size_t)row * GF + (K0) + c * 8];     \
        }                                                                     \
        _Pragma("unroll")                                                     \
        for (int it = 0; it < 4; ++it) {                                      \
            int idx = it * 256 + tid, row = idx >> 3, c = idx & 7;            \
            wr[it] = *(const uint4*)&Wp[(size_t)row * GF + (K0) + c * 8];     \
        }                                                                     \
    }

#define STORE_TILE()                                                          \
    {                                                                         \
        _Pragma("unroll")                                                     \
        for (int it = 0; it < 2; ++it) {                                      \
            int idx = it * 256 + tid, row = idx >> 3, c = idx & 7;            \
            *(uint4*)&sX[row * XS + c * 8] = xr[it];                          \
        }                                                                     \
        _Pragma("unroll")                                                     \
        for (int it = 0; it < 4; ++it) {                                      \
            int idx = it * 256 + tid, row = idx >> 3, c = idx & 7;            \
            *(uint4*)&sW[row * XS + c * 8] = wr[it];                          \
        }                                                                     \
    }

    f32x4 acc[8];
#pragma unroll
    for (int nt = 0; nt < 8; ++nt) acc[nt] = (f32x4){0.f, 0.f, 0.f, 0.f};

    ISSUE_TILE(0)
    STORE_TILE()

    for (int k0 = 0; k0 < GF; k0 += 64) {
        __syncthreads();                       // tile k0 visible
        if (k0 + 64 < GF) ISSUE_TILE(k0 + 64)  // next tile in flight

#pragma unroll
        for (int ks = 0; ks < 64; ks += 32) {
            bf16x8 af = *(const bf16x8*)&sX[(wv * 16 + lm) * XS + ks + q * 8];
            bf16x8 bfr[8];
#pragma unroll
            for (int nt = 0; nt < 8; ++nt)
                bfr[nt] = *(const bf16x8*)&sW[(nt * 16 + lm) * XS + ks + q * 8];
#pragma unroll
            for (int nt = 0; nt < 8; ++nt)
                acc[nt] = __builtin_amdgcn_mfma_f32_16x16x32_bf16(
                    af, bfr[nt], acc[nt], 0, 0, 0);
        }
        __syncthreads();                       // readers done
        if (k0 + 64 < GF) STORE_TILE()
    }
#undef ISSUE_TILE
#undef STORE_TILE

    // epilogue: bf16 feats store + fused s_self/s_neigh from fp32 accs
    float aS[8], aN[8];
#pragma unroll
    for (int nt = 0; nt < 8; ++nt) {
        aS[nt] = a_self[h * GC + nt * 16 + lm];
        aN[nt] = a_neigh[h * GC + nt * 16 + lm];
    }
    float vs[4] = {0.f, 0.f, 0.f, 0.f};
    float vn[4] = {0.f, 0.f, 0.f, 0.f};
    int rbase = n0 + wv * 16 + q * 4;          // D row = quad*4+reg (m89)
#pragma unroll
    for (int nt = 0; nt < 8; ++nt) {
        f32x4 v = acc[nt];
        int col = nt * 16 + lm;                // D col = lane&15
#pragma unroll
        for (int r = 0; r < 4; ++r) {
            featsb[((size_t)h * GN + rbase + r) * GC + col] = __float2bfloat16(v[r]);
            vs[r] += v[r] * aS[nt];
            vn[r] += v[r] * aN[nt];
        }
    }
#pragma unroll
    for (int r = 0; r < 4; ++r) {
        for (int off = 1; off < 16; off <<= 1) {
            vs[r] += __shfl_xor(vs[r], off);
            vn[r] += __shfl_xor(vn[r], off);
        }
        if (lm == 0) {
            s_self[h * GN + rbase + r]  = vs[r];
            s_neigh[h * GN + rbase + r] = vn[r];
        }
    }
}

// ---------------------------------------------------------------------------
// Kernel 3 (attn — r13-measured-best): ONE WAVE per (2 heads, i), 16384
// waves -> 4096 blocks. List loaded once per wave; gather from two
// head-slabs per neighbor (2 independent loads in flight); even/odd-k
// split accumulators. Zero barriers; wave-shuffle softmax.
// ---------------------------------------------------------------------------
__global__ __launch_bounds__(256) void attn_kernel(
    const int* __restrict__ deg, const u16* __restrict__ lists,
    const float* __restrict__ bias, const bf16* __restrict__ featsb,
    const float* __restrict__ s_self, const float* __restrict__ s_neigh,
    float* __restrict__ out)
{
    int tid  = threadIdx.x;
    int wv   = tid >> 6, lane = tid & 63;
    int g    = blockIdx.x * 4 + wv;        // 0..16383, head-pair-major
    int hp   = g >> 12;                    // 0..3
    int i    = g & (GN - 1);
    int h0   = hp * 2, h1 = h0 + 1;

    __shared__ float4 pjbuf[4][CAP];       // 16 KB
    float4* pj = pjbuf[wv];

    int M = deg[i];
    const u16* row = lists + (size_t)i * CAP;
    float ssi0 = s_self[h0 * GN + i];
    float ssi1 = s_self[h1 * GN + i];
    const float* sn0 = s_neigh + (size_t)h0 * GN;
    const float* sn1 = s_neigh + (size_t)h1 * GN;

    // pass 1: leaky scores for both heads -> LDS, lane-local max
    float m0 = -1e30f, m1 = -1e30f;
    for (int k = lane; k < M; k += 64) {
        int j = row[k];
        float e0 = ssi0 + sn0[j]; e0 = e0 > 0.f ? e0 : 0.2f * e0;
        float e1 = ssi1 + sn1[j]; e1 = e1 > 0.f ? e1 : 0.2f * e1;
        pj[k] = make_float4(e0, e1, __int_as_float(j), 0.f);
        m0 = fmaxf(m0, e0);
        m1 = fmaxf(m1, e1);
    }
#pragma unroll
    for (int off = 32; off > 0; off >>= 1) {
        m0 = fmaxf(m0, __shfl_xor(m0, off));
        m1 = fmaxf(m1, __shfl_xor(m1, off));
    }

    // pass 2: exp in place + sums
    float s0 = 0.f, s1 = 0.f;
    for (int k = lane; k < M; k += 64) {
        float4 v = pj[k];
        float e0 = __expf(v.x - m0);
        float e1 = __expf(v.y - m1);
        pj[k].x = e0;
        pj[k].y = e1;
        s0 += e0;
        s1 += e1;
    }
#pragma unroll
    for (int off = 32; off > 0; off >>= 1) {
        s0 += __shfl_xor(s0, off);
        s1 += __shfl_xor(s1, off);
    }
    float inv0 = 1.f / s0, inv1 = 1.f / s1;

    // gather: lane owns dword (channels 2*lane, 2*lane+1) in both head slabs
    const u32* f0 = (const u32*)(featsb + (size_t)h0 * GN * GC) + lane;
    const u32* f1 = (const u32*)(featsb + (size_t)h1 * GN * GC) + lane;
    float aE0 = 0.f, aE1 = 0.f, bE0 = 0.f, bE1 = 0.f;   // even k
    float aO0 = 0.f, aO1 = 0.f, bO0 = 0.f, bO1 = 0.f;   // odd k
    int k = 0;
    for (; k + 2 <= M; k += 2) {
        float4 v0 = pj[k], v1 = pj[k + 1];
        int j0 = __float_as_int(v0.z), j1 = __float_as_int(v1.z);
        u32 u00 = f0[(size_t)j0 << 6];
        u32 u10 = f1[(size_t)j0 << 6];
        u32 u01 = f0[(size_t)j1 << 6];
        u32 u11 = f1[(size_t)j1 << 6];
        aE0 += v0.x * __uint_as_float(u00 << 16);
        aE1 += v0.x * __uint_as_float(u00 & 0xffff0000u);
        bE0 += v0.y * __uint_as_float(u10 << 16);
        bE1 += v0.y * __uint_as_float(u10 & 0xffff0000u);
        aO0 += v1.x * __uint_as_float(u01 << 16);
        aO1 += v1.x * __uint_as_float(u01 & 0xffff0000u);
        bO0 += v1.y * __uint_as_float(u11 << 16);
        bO1 += v1.y * __uint_as_float(u11 & 0xffff0000u);
    }
    if (k < M) {
        float4 v0 = pj[k];
        int j0 = __float_as_int(v0.z);
        u32 u00 = f0[(size_t)j0 << 6];
        u32 u10 = f1[(size_t)j0 << 6];
        aE0 += v0.x * __uint_as_float(u00 << 16);
        aE1 += v0.x * __uint_as_float(u00 & 0xffff0000u);
        bE0 += v0.y * __uint_as_float(u10 << 16);
        bE1 += v0.y * __uint_as_float(u10 & 0xffff0000u);
    }

    const float2 bv0 = *(const float2*)&bias[h0 * GC + 2 * lane];
    const float2 bv1 = *(const float2*)&bias[h1 * GC + 2 * lane];
    size_t ob = (size_t)i * (GH * GC);
    float2* op0 = (float2*)&out[ob + h0 * GC + 2 * lane];
    float2* op1 = (float2*)&out[ob + h1 * GC + 2 * lane];
    *op0 = make_float2(fmaxf((aE0 + aO0) * inv0 + bv0.x, 0.f),
                       fmaxf((aE1 + aO1) * inv0 + bv0.y, 0.f));
    *op1 = make_float2(fmaxf((bE0 + bO0) * inv1 + bv1.x, 0.f),
                       fmaxf((bE1 + bO1) * inv1 + bv1.y, 0.f));
}

// ---------------------------------------------------------------------------
extern "C" void kernel_launch(void* const* d_in, const int* in_sizes, int n_in,
                              void* d_out, int out_size, void* d_ws, size_t ws_size,
                              hipStream_t stream)
{
    const float* X       = (const float*)d_in[0];
    const float* A       = (const float*)d_in[1];
    const float* W       = (const float*)d_in[2];
    const float* a_self  = (const float*)d_in[3];
    const float* a_neigh = (const float*)d_in[4];
    const float* bias    = (const float*)d_in[5];
    float* out = (float*)d_out;

    // ws layout: featsb bf16 [H*N*C] | s_self f32 [H*N] | s_neigh f32 [H*N]
    //            | deg i32 [N] | lists u16 [N*CAP] | Xb u16 [N*F] | WT u16 [H*C*F]
    bf16*  featsb  = (bf16*)d_ws;
    float* s_self  = (float*)(featsb + (size_t)GH * GN * GC);
    float* s_neigh = s_self + (size_t)GH * GN;
    int*   deg     = (int*)(s_neigh + (size_t)GH * GN);
    u16*   lists   = (u16*)(deg + GN);
    u16*   Xb      = lists + (size_t)GN * CAP;
    u16*   WT      = Xb + (size_t)GN * GF;

    prep_csr_kernel<<<1088 + GN, 256, 0, stream>>>(A, X, W, deg, lists, Xb, WT);
    feats_kernel<<<GH * 64, 256, 0, stream>>>(Xb, WT, a_self, a_neigh,
                                              featsb, s_self, s_neigh);
    attn_kernel<<<GH * GN / 8, 256, 0, stream>>>(deg, lists, bias, featsb,
                                                 s_self, s_neigh, out);
}